// Round 10
// baseline (544.771 us; speedup 1.0000x reference)
//
#include <hip/hip_runtime.h>
#include <hip/hip_bf16.h>

typedef unsigned short u16;
typedef unsigned int u32;
typedef __attribute__((ext_vector_type(8))) short bf16x8;   // 8 bf16 = 4 VGPRs
typedef __attribute__((ext_vector_type(4))) short bf16x4;
typedef __attribute__((ext_vector_type(4))) float f32x4;

#define NBG   5000
#define NPID  5532
#define NTOT  15532      // 5000 + 5532 + 5000
#define FEAT  256
#define BATCH 4096
#define SCALE_LOG2E 43.280851226668994f   // 30 * log2(e)
#define LPITCH 264       // f32-fallback LDS pitch (shorts)

#define NTILE_B  976             // 61 chunks x 16 tiles; 971 real, 5 zero-pad
#define TILE_SH  4096            // shorts per 16-col tile (16*256)
#define NTILE_A  256             // 4096 rows / 16

// ---- workspace layout (bytes) ----
#define TABT_BYTES ((size_t)NTILE_B * TILE_SH * 2)   // 7,995,392
#define AT_BYTES   ((size_t)NTILE_A * TILE_SH * 2)   // 2,097,152
#define SUMS_OFF   (TABT_BYTES + AT_BYTES)
// S floats: [0,4096) bg | [4096,8192) nb | 8192 det | 8193 oim | 8194 nv
//           | 8195 gticket(u32) | 8196..8211 rc_ticket[16](u32)
#define SUMS_FLOATS 8212
#define WS_NEED    (SUMS_OFF + SUMS_FLOATS * 4)

__device__ __forceinline__ void atomic_add_f(float* p, float v) {
    __hip_atomic_fetch_add(p, v, __ATOMIC_RELAXED, __HIP_MEMORY_SCOPE_AGENT);
}
__device__ __forceinline__ float atomic_ld_f(const float* p) {
    return __hip_atomic_load(p, __ATOMIC_RELAXED, __HIP_MEMORY_SCOPE_AGENT);
}
__device__ __forceinline__ short f2bf(float f) {
    return (short)__bfloat16_as_ushort(__float2bfloat16(f));
}
__device__ __forceinline__ float bf2f(u16 u) {
    union { u32 i; float f; } v; v.i = ((u32)u) << 16; return v.f;
}

__device__ __forceinline__ const float* table_row(
    int n, const float* __restrict__ lut, const float* __restrict__ cq,
    const float* __restrict__ cqb)
{
    const int nc = n < NTOT ? n : NTOT - 1;
    if (nc < NBG)        return cqb + (size_t)nc * FEAT;
    if (nc < NBG + NPID) return lut + (size_t)(nc - NBG) * FEAT;
    return cq + (size_t)(nc - NBG - NPID) * FEAT;
}

// -------- Stage 0: f32 -> bf16 tiled prepass (table + inputs) + zero sums --
// Tile format (8192 B per 16-col tile): short off = kk*512 + q*128 + col*8,
// holding src[col][kk*32 + q*8 .. +8]. A wave's frag read of (kk, quad, l15)
// is byte kk*1024 + quad*256 + l15*16 -> consecutive 8 lanes hit 8 distinct
// LDS bank-groups (conflict-free) AND global reads are 1 KB contiguous.
#define TAB_UNITS (NTILE_B * 512)    // 499,712
#define A_UNITS   (NTILE_A * 512)    // 131,072
#define PRE_BLOCKS ((TAB_UNITS + A_UNITS) / 256)   // 2464

__global__ __launch_bounds__(256) void prepass_kernel(
    const float* __restrict__ inputs, const float* __restrict__ lut,
    const float* __restrict__ cq, const float* __restrict__ cqb,
    u16* __restrict__ tabt, u16* __restrict__ at, float* __restrict__ S)
{
    const int u = blockIdx.x * 256 + threadIdx.x;
    if (u < SUMS_FLOATS) S[u] = 0.f;

    if (u < TAB_UNITS) {
        const int tile = u >> 9, v = u & 511;
        const int kk = v >> 6, q = (v >> 4) & 3, col = v & 15;
        const int cg = tile * 16 + col;
        bf16x8 r = {0, 0, 0, 0, 0, 0, 0, 0};
        if (cg < NTOT) {
            const float* src = table_row(cg, lut, cq, cqb) + kk * 32 + q * 8;
            const f32x4 lo = *(const f32x4*)src;
            const f32x4 hi = *(const f32x4*)(src + 4);
            r = bf16x8{ f2bf(lo[0]), f2bf(lo[1]), f2bf(lo[2]), f2bf(lo[3]),
                        f2bf(hi[0]), f2bf(hi[1]), f2bf(hi[2]), f2bf(hi[3]) };
        }
        *(bf16x8*)(tabt + (size_t)u * 8) = r;
    } else {
        const int ua = u - TAB_UNITS;
        const int tile = ua >> 9, v = ua & 511;
        const int kk = v >> 6, q = (v >> 4) & 3, row = v & 15;
        const float* src = inputs + (size_t)(tile * 16 + row) * FEAT + kk * 32 + q * 8;
        const f32x4 lo = *(const f32x4*)src;
        const f32x4 hi = *(const f32x4*)(src + 4);
        bf16x8 r = { f2bf(lo[0]), f2bf(lo[1]), f2bf(lo[2]), f2bf(lo[3]),
                     f2bf(hi[0]), f2bf(hi[1]), f2bf(hi[2]), f2bf(hi[3]) };
        *(bf16x8*)(at + (size_t)ua * 8) = r;
    }
}

// -------- Stage 1: fused GEMM + exp-sum + per-rowchunk finalize ------------
// 976 blocks (16 rowchunks x 61 colchunks), XCD-swizzled. LDS-shared B,
// double-buffered, ONE barrier/tile, 2-tile-deep register prefetch.
// The LAST block of each rowchunk (ticket) finalizes its 256 rows inline;
// a 16-way global ticket publishes the two loss scalars.
__global__ __launch_bounds__(256, 2) void score_bf16_kernel(
    const u16* __restrict__ tabt, const u16* __restrict__ at,
    const int* __restrict__ roi, float* __restrict__ S,
    float* __restrict__ out)
{
    __shared__ __align__(16) short lbuf[2][TILE_SH];
    __shared__ float red[12];
    __shared__ u32 sflag;

    float* sum_bg = S;
    float* sum_nb = S + BATCH;
    float* acc    = S + 2 * BATCH;                 // det, oim, nv
    u32*   gt     = (u32*)(S + 2 * BATCH + 3);
    u32*   rct    = (u32*)(S + 2 * BATCH + 4);     // [16]

    const int lid = blockIdx.x;
    const int x8  = lid & 7;
    const int j   = lid >> 3;                 // [0, 122)
    const int rowchunk = x8 * 2 + (j & 1);    // [0, 16)
    const int colchunk = j >> 1;              // [0, 61)

    const int tid  = threadIdx.x;
    const int wave = tid >> 6;
    const int lane = tid & 63;
    const int l15  = lane & 15;
    const int quad = lane >> 4;

    // A fragments: 4 row-tiles, coalesced 1 KB/wave reads (live in AGPRs).
    bf16x8 af[4][8];
    {
        const u16* ab = at + (size_t)(rowchunk * 16 + wave * 4) * TILE_SH
                           + quad * 128 + l15 * 8;
        #pragma unroll
        for (int s = 0; s < 4; ++s)
            #pragma unroll
            for (int kk = 0; kk < 8; ++kk)
                af[s][kk] = *(const bf16x8*)(ab + (size_t)s * TILE_SH + kk * 512);
    }

    float pbg[16], pnb[16];
    #pragma unroll
    for (int i = 0; i < 16; ++i) { pbg[i] = 0.f; pnb[i] = 0.f; }

    const int bt0  = colchunk * 16;
    const int tmax = (colchunk == 60) ? 11 : 16;   // tiles 971..975 are all-pad

    // 2-deep register prefetch: rg[sel] holds tile (t) when entering iter t.
    bf16x8 rg[2][2];
    {
        const u16* g = tabt + (size_t)bt0 * TILE_SH;
        rg[0][0] = *(const bf16x8*)(g + tid * 8);
        rg[0][1] = *(const bf16x8*)(g + 2048 + tid * 8);
        const u16* g1 = g + TILE_SH;
        rg[1][0] = *(const bf16x8*)(g1 + tid * 8);
        rg[1][1] = *(const bf16x8*)(g1 + 2048 + tid * 8);
    }

    #pragma unroll 1
    for (int t = 0; t < tmax; ++t) {
        const int bt  = bt0 + t;               // global 16-col tile index
        const int sel = t & 1;
        {
            short* dst = lbuf[sel];
            *(bf16x8*)(dst + tid * 8) = rg[sel][0];
            *(bf16x8*)(dst + 2048 + tid * 8) = rg[sel][1];
        }
        if (t + 2 < tmax) {                    // prefetch t+2 into freed regs
            const u16* g = tabt + (size_t)(bt + 2) * TILE_SH;
            rg[sel][0] = *(const bf16x8*)(g + tid * 8);
            rg[sel][1] = *(const bf16x8*)(g + 2048 + tid * 8);
        }
        __syncthreads();                       // tile t visible to all waves

        const short* lb = lbuf[sel];
        f32x4 cc[4];
        #pragma unroll
        for (int s = 0; s < 4; ++s) cc[s] = f32x4{0.f, 0.f, 0.f, 0.f};
        #pragma unroll
        for (int kk = 0; kk < 8; ++kk) {
            const bf16x8 b = *(const bf16x8*)(lb + kk * 512 + quad * 128 + l15 * 8);
            cc[0] = __builtin_amdgcn_mfma_f32_16x16x32_bf16(af[0][kk], b, cc[0], 0, 0, 0);
            cc[1] = __builtin_amdgcn_mfma_f32_16x16x32_bf16(af[1][kk], b, cc[1], 0, 0, 0);
            cc[2] = __builtin_amdgcn_mfma_f32_16x16x32_bf16(af[2][kk], b, cc[2], 0, 0, 0);
            cc[3] = __builtin_amdgcn_mfma_f32_16x16x32_bf16(af[3][kk], b, cc[3], 0, 0, 0);
        }

        if (colchunk != 60) {
            if (bt < 312) {                    // all background
                #pragma unroll
                for (int s = 0; s < 4; ++s)
                    #pragma unroll
                    for (int r = 0; r < 4; ++r)
                        pbg[s * 4 + r] += exp2f(cc[s][r] * SCALE_LOG2E);
            } else if (bt > 312) {             // all non-bg
                #pragma unroll
                for (int s = 0; s < 4; ++s)
                    #pragma unroll
                    for (int r = 0; r < 4; ++r)
                        pnb[s * 4 + r] += exp2f(cc[s][r] * SCALE_LOG2E);
            } else {                           // tile 312: cols 4992..5007
                const bool isbg = l15 < 8;
                #pragma unroll
                for (int s = 0; s < 4; ++s)
                    #pragma unroll
                    for (int r = 0; r < 4; ++r) {
                        const float e = exp2f(cc[s][r] * SCALE_LOG2E);
                        pbg[s * 4 + r] += isbg ? e : 0.f;
                        pnb[s * 4 + r] += isbg ? 0.f : e;
                    }
            }
        } else {                               // last chunk: mask pad cols
            const bool okc = (bt * 16 + l15) < NTOT;
            #pragma unroll
            for (int s = 0; s < 4; ++s)
                #pragma unroll
                for (int r = 0; r < 4; ++r) {
                    const float e = exp2f(cc[s][r] * SCALE_LOG2E);
                    pnb[s * 4 + r] += okc ? e : 0.f;
                }
        }
    }

    #pragma unroll
    for (int off = 1; off < 16; off <<= 1) {
        #pragma unroll
        for (int i = 0; i < 16; ++i) {
            pbg[i] += __shfl_xor(pbg[i], off);
            pnb[i] += __shfl_xor(pnb[i], off);
        }
    }
    if (l15 == 0) {
        #pragma unroll
        for (int s = 0; s < 4; ++s) {
            #pragma unroll
            for (int r = 0; r < 4; ++r) {
                const int row = (rowchunk * 16 + wave * 4 + s) * 16 + quad * 4 + r;
                atomic_add_f(&sum_bg[row], pbg[s * 4 + r]);
                atomic_add_f(&sum_nb[row], pnb[s * 4 + r]);
            }
        }
    }

    // ---- per-rowchunk ticket: last of 61 blocks finalizes its 256 rows ----
    __syncthreads();                           // all waves' atomics issued
    if (tid == 0) {
        __threadfence();
        const u32 tt = __hip_atomic_fetch_add(&rct[rowchunk], 1u,
                                              __ATOMIC_ACQ_REL, __HIP_MEMORY_SCOPE_AGENT);
        sflag = (tt == 60) ? 1u : 0u;
    }
    __syncthreads();
    if (sflag) {
        const int row = rowchunk * 256 + tid;
        const int r   = roi[row];

        // dot(inputs[row], lut[clamp(r)]) from the bf16 tiled buffers
        // (identical quantization to the GEMM).
        const int lr = NBG + (r < 0 ? 0 : r);
        const u16* arow = at   + (size_t)(row >> 4) * TILE_SH + (row & 15) * 8;
        const u16* brow = tabt + (size_t)(lr  >> 4) * TILE_SH + (lr  & 15) * 8;
        float dot = 0.f;
        #pragma unroll 4
        for (int c = 0; c < 32; ++c) {         // c = kk*4 + q
            const bf16x8 av = *(const bf16x8*)(arow + c * 128);
            const bf16x8 bv = *(const bf16x8*)(brow + c * 128);
            #pragma unroll
            for (int jj = 0; jj < 8; ++jj)
                dot += bf2f((u16)av[jj]) * bf2f((u16)bv[jj]);
        }

        const float sbg = atomic_ld_f(&sum_bg[row]);
        const float snb = atomic_ld_f(&sum_nb[row]);
        const float inv = 1.f / (sbg + snb);
        const float cls0 = sbg * inv;
        const float cls1 = snb * inv;
        out[2 * row]     = cls0;
        out[2 * row + 1] = cls1;

        const float cs = (r >= -1) ? cls1 : cls0;
        const float om = 1.f - cs;
        float det_c = -(0.25f * om * om * logf(cs)) * (1.f / (float)BATCH);
        float nv_c  = (r >= -1) ? 1.f : 0.f;
        float oim_c = 0.f;
        if (r >= 0) {
            const float logp = 30.f * dot - logf(snb);
            const float p    = expf(logp);
            const float om2  = 1.f - p;
            oim_c = -(0.25f * om2 * om2 * logp) * cls1 * cls1;
        }

        #pragma unroll
        for (int off = 32; off > 0; off >>= 1) {
            det_c += __shfl_xor(det_c, off);
            oim_c += __shfl_xor(oim_c, off);
            nv_c  += __shfl_xor(nv_c,  off);
        }
        if (lane == 0) { red[wave*3] = det_c; red[wave*3+1] = oim_c; red[wave*3+2] = nv_c; }
        __syncthreads();
        if (tid == 0) {
            atomic_add_f(&acc[0], red[0] + red[3] + red[6] + red[9]);
            atomic_add_f(&acc[1], red[1] + red[4] + red[7] + red[10]);
            atomic_add_f(&acc[2], red[2] + red[5] + red[8] + red[11]);
            __threadfence();
            const u32 g = __hip_atomic_fetch_add(gt, 1u, __ATOMIC_ACQ_REL,
                                                 __HIP_MEMORY_SCOPE_AGENT);
            if (g == 15) {
                const float det = atomic_ld_f(&acc[0]);
                const float oim = atomic_ld_f(&acc[1]);
                float nv        = atomic_ld_f(&acc[2]);
                if (nv < 1.f) nv = 1.f;
                out[2 * BATCH]     = det;
                out[2 * BATCH + 1] = oim / nv;
            }
        }
    }
}

// -------- f32 fallback path (round-4 structure + separate finalize) --------
__global__ __launch_bounds__(256, 2) void score_f32_kernel(
    const float* __restrict__ inputs, const float* __restrict__ lut,
    const float* __restrict__ cq, const float* __restrict__ cqb,
    float* __restrict__ sum_bg, float* __restrict__ sum_nb)
{
    __shared__ __align__(16) short lds[32 * LPITCH];
    const int wave = threadIdx.x >> 6;
    const int lane = threadIdx.x & 63;
    const int l15  = lane & 15;
    const int quad = lane >> 4;
    const int rowbase = blockIdx.y * 256;
    const int colbase = blockIdx.x * 256;

    bf16x8 afrag[4][8];
    #pragma unroll 1
    for (int c = 0; c < 8; ++c) {
        __syncthreads();
        #pragma unroll
        for (int i = 0; i < 8; ++i) {
            const int lr = i * 4 + wave;
            const f32x4 v = *(const f32x4*)(inputs + (size_t)(rowbase + c * 32 + lr) * FEAT + lane * 4);
            bf16x4 h = { f2bf(v[0]), f2bf(v[1]), f2bf(v[2]), f2bf(v[3]) };
            *(bf16x4*)(&lds[lr * LPITCH + lane * 4]) = h;
        }
        __syncthreads();
        if ((c >> 1) == wave) {
            const int half = c & 1;
            #pragma unroll
            for (int j2 = 0; j2 < 2; ++j2) {
                const int lr = j2 * 16 + l15;
                #pragma unroll
                for (int kk = 0; kk < 8; ++kk)
                    afrag[half * 2 + j2][kk] =
                        *(const bf16x8*)(&lds[lr * LPITCH + kk * 32 + quad * 8]);
            }
        }
    }

    float pbg[16], pnb[16];
    #pragma unroll
    for (int i = 0; i < 16; ++i) { pbg[i] = 0.f; pnb[i] = 0.f; }

    #pragma unroll 1
    for (int s = 0; s < 8; ++s) {
        __syncthreads();
        #pragma unroll
        for (int i = 0; i < 8; ++i) {
            const int lc = i * 4 + wave;
            const f32x4 v = *(const f32x4*)(table_row(colbase + s * 32 + lc, lut, cq, cqb) + lane * 4);
            bf16x4 h = { f2bf(v[0]), f2bf(v[1]), f2bf(v[2]), f2bf(v[3]) };
            *(bf16x4*)(&lds[lc * LPITCH + lane * 4]) = h;
        }
        __syncthreads();

        #pragma unroll
        for (int st = 0; st < 2; ++st) {
            const int lc = st * 16 + l15;
            f32x4 cc[4];
            #pragma unroll
            for (int q = 0; q < 4; ++q) cc[q] = f32x4{0.f, 0.f, 0.f, 0.f};
            #pragma unroll
            for (int kk = 0; kk < 8; ++kk) {
                const bf16x8 b = *(const bf16x8*)(&lds[lc * LPITCH + kk * 32 + quad * 8]);
                cc[0] = __builtin_amdgcn_mfma_f32_16x16x32_bf16(afrag[0][kk], b, cc[0], 0, 0, 0);
                cc[1] = __builtin_amdgcn_mfma_f32_16x16x32_bf16(afrag[1][kk], b, cc[1], 0, 0, 0);
                cc[2] = __builtin_amdgcn_mfma_f32_16x16x32_bf16(afrag[2][kk], b, cc[2], 0, 0, 0);
                cc[3] = __builtin_amdgcn_mfma_f32_16x16x32_bf16(afrag[3][kk], b, cc[3], 0, 0, 0);
            }
            const int n = colbase + s * 32 + st * 16 + l15;
            const bool okc  = n < NTOT;
            const bool isbg = n < NBG;
            #pragma unroll
            for (int q = 0; q < 4; ++q) {
                #pragma unroll
                for (int r = 0; r < 4; ++r) {
                    float e = exp2f(cc[q][r] * SCALE_LOG2E);
                    e = okc ? e : 0.f;
                    pbg[q * 4 + r] += isbg ? e : 0.f;
                    pnb[q * 4 + r] += isbg ? 0.f : e;
                }
            }
        }
    }

    #pragma unroll
    for (int off = 1; off < 16; off <<= 1) {
        #pragma unroll
        for (int i = 0; i < 16; ++i) {
            pbg[i] += __shfl_xor(pbg[i], off);
            pnb[i] += __shfl_xor(pnb[i], off);
        }
    }
    if (l15 == 0) {
        #pragma unroll
        for (int q = 0; q < 4; ++q) {
            #pragma unroll
            for (int r = 0; r < 4; ++r) {
                const int row = rowbase + wave * 64 + q * 16 + quad * 4 + r;
                atomic_add_f(&sum_bg[row], pbg[q * 4 + r]);
                atomic_add_f(&sum_nb[row], pnb[q * 4 + r]);
            }
        }
    }
}

__global__ __launch_bounds__(256) void finalize_kernel(
    const float* __restrict__ inputs, const int* __restrict__ roi_label,
    const float* __restrict__ lut,
    const float* __restrict__ sum_bg, const float* __restrict__ sum_nb,
    float* __restrict__ accums, unsigned int* __restrict__ ticket,
    float* __restrict__ out)
{
    __shared__ float s_det[4], s_oim[4], s_nv[4];
    const int wid  = threadIdx.x >> 6;
    const int lane = threadIdx.x & 63;

    float det_a = 0.f, oim_a = 0.f, nv_a = 0.f;

    #pragma unroll 1
    for (int it = 0; it < 8; ++it) {
        const int row = blockIdx.x * 32 + wid * 8 + it;
        const int r   = roi_label[row];

        float dot = 0.f;
        {
            const int rc = r < 0 ? 0 : r;
            const f32x4 xi = *(const f32x4*)(inputs + (size_t)row * FEAT + lane * 4);
            const f32x4 li = *(const f32x4*)(lut + (size_t)rc * FEAT + lane * 4);
            #pragma unroll
            for (int jj = 0; jj < 4; ++jj)
                dot += bf2f((u16)f2bf(xi[jj])) * bf2f((u16)f2bf(li[jj]));
        }
        #pragma unroll
        for (int off = 32; off > 0; off >>= 1) dot += __shfl_xor(dot, off);

        if (lane == 0) {
            const float sbg = sum_bg[row];
            const float snb = sum_nb[row];
            const float inv = 1.f / (sbg + snb);
            const float cls0 = sbg * inv;
            const float cls1 = snb * inv;
            out[2 * row]     = cls0;
            out[2 * row + 1] = cls1;

            const float cs = (r >= -1) ? cls1 : cls0;
            const float om = 1.f - cs;
            det_a += -(0.25f * om * om * logf(cs)) * (1.f / (float)BATCH);
            nv_a  += (r >= -1) ? 1.f : 0.f;

            if (r >= 0) {
                const float logp = 30.f * dot - logf(snb);
                const float p    = expf(logp);
                const float om2  = 1.f - p;
                oim_a += -(0.25f * om2 * om2 * logp) * cls1 * cls1;
            }
        }
    }

    if (lane == 0) { s_det[wid] = det_a; s_oim[wid] = oim_a; s_nv[wid] = nv_a; }
    __syncthreads();
    if (threadIdx.x == 0) {
        atomic_add_f(&accums[0], s_det[0] + s_det[1] + s_det[2] + s_det[3]);
        atomic_add_f(&accums[1], s_oim[0] + s_oim[1] + s_oim[2] + s_oim[3]);
        atomic_add_f(&accums[2], s_nv[0] + s_nv[1] + s_nv[2] + s_nv[3]);
        __threadfence();
        const unsigned t = __hip_atomic_fetch_add(ticket, 1u, __ATOMIC_ACQ_REL,
                                                  __HIP_MEMORY_SCOPE_AGENT);
        if (t == gridDim.x - 1) {
            const float det = atomic_ld_f(&accums[0]);
            const float oim = atomic_ld_f(&accums[1]);
            float nv        = atomic_ld_f(&accums[2]);
            if (nv < 1.f) nv = 1.f;
            out[2 * BATCH]     = det;
            out[2 * BATCH + 1] = oim / nv;
        }
    }
}

extern "C" void kernel_launch(void* const* d_in, const int* in_sizes, int n_in,
                              void* d_out, int out_size, void* d_ws, size_t ws_size,
                              hipStream_t stream)
{
    const float* inputs = (const float*)d_in[0];
    const int*   roi    = (const int*)d_in[1];
    const float* lut    = (const float*)d_in[2];
    const float* cq     = (const float*)d_in[3];
    const float* cqb    = (const float*)d_in[4];
    float* out = (float*)d_out;

    if (ws_size >= (size_t)WS_NEED) {
        u16* tabt = (u16*)d_ws;
        u16* at   = (u16*)((char*)d_ws + TABT_BYTES);
        float* S  = (float*)((char*)d_ws + SUMS_OFF);
        prepass_kernel<<<PRE_BLOCKS, 256, 0, stream>>>(inputs, lut, cq, cqb, tabt, at, S);
        score_bf16_kernel<<<976, 256, 0, stream>>>(tabt, at, roi, S, out);
    } else {
        float* S = (float*)d_ws;
        hipMemsetAsync(S, 0, SUMS_FLOATS * sizeof(float), stream);
        dim3 g1(61, 16);
        score_f32_kernel<<<g1, 256, 0, stream>>>(inputs, lut, cq, cqb, S, S + BATCH);
        finalize_kernel<<<128, 256, 0, stream>>>(
            inputs, roi, lut, S, S + BATCH, S + 2 * BATCH,
            (unsigned int*)(S + 2 * BATCH + 3), out);
    }
}

// Round 11
// 188.247 us; speedup vs baseline: 2.8939x; 2.8939x over previous
//
#include <hip/hip_runtime.h>
#include <hip/hip_bf16.h>

typedef unsigned short u16;
typedef unsigned int u32;
typedef __attribute__((ext_vector_type(8))) short bf16x8;   // 8 bf16 = 4 VGPRs
typedef __attribute__((ext_vector_type(4))) short bf16x4;
typedef __attribute__((ext_vector_type(4))) float f32x4;

#define NBG   5000
#define NPID  5532
#define NTOT  15532      // 5000 + 5532 + 5000
#define FEAT  256
#define BATCH 4096
#define SCALE_LOG2E 43.280851226668994f   // 30 * log2(e)
#define LPITCH 264       // f32-fallback LDS pitch (shorts)

#define NTILE_B  976             // 61 chunks x 16 tiles; 971 real, 5 zero-pad
#define TILE_SH  4096            // shorts per 16-col tile (16*256)
#define NTILE_A  256             // 4096 rows / 16

// ---- workspace layout (bytes) ----
#define TABT_BYTES ((size_t)NTILE_B * TILE_SH * 2)   // 7,995,392
#define AT_BYTES   ((size_t)NTILE_A * TILE_SH * 2)   // 2,097,152
#define SUMS_OFF   (TABT_BYTES + AT_BYTES)
// S floats: [0,4096) bg | [4096,8192) nb | 8192 det | 8193 oim | 8194 nv
//           | 8195 gticket(u32) | 8196..8211 rc_ticket[16](u32)
#define SUMS_FLOATS 8212
#define WS_NEED    (SUMS_OFF + SUMS_FLOATS * 4)

__device__ __forceinline__ void atomic_add_f(float* p, float v) {
    __hip_atomic_fetch_add(p, v, __ATOMIC_RELAXED, __HIP_MEMORY_SCOPE_AGENT);
}
__device__ __forceinline__ float atomic_ld_f(const float* p) {
    return __hip_atomic_load(p, __ATOMIC_RELAXED, __HIP_MEMORY_SCOPE_AGENT);
}
__device__ __forceinline__ short f2bf(float f) {
    return (short)__bfloat16_as_ushort(__float2bfloat16(f));
}
__device__ __forceinline__ float bf2f(u16 u) {
    union { u32 i; float f; } v; v.i = ((u32)u) << 16; return v.f;
}

__device__ __forceinline__ const float* table_row(
    int n, const float* __restrict__ lut, const float* __restrict__ cq,
    const float* __restrict__ cqb)
{
    const int nc = n < NTOT ? n : NTOT - 1;
    if (nc < NBG)        return cqb + (size_t)nc * FEAT;
    if (nc < NBG + NPID) return lut + (size_t)(nc - NBG) * FEAT;
    return cq + (size_t)(nc - NBG - NPID) * FEAT;
}

// -------- Stage 0: f32 -> bf16 tiled prepass (table + inputs) + zero sums --
// Tile format (8192 B per 16-col tile): short off = kk*512 + q*128 + col*8,
// holding src[col][kk*32 + q*8 .. +8]. A wave's frag read of (kk, quad, l15)
// is byte kk*1024 + quad*256 + l15*16 -> consecutive 8 lanes hit 8 distinct
// LDS bank-groups (conflict-free) AND global reads are 1 KB contiguous.
#define TAB_UNITS (NTILE_B * 512)    // 499,712
#define A_UNITS   (NTILE_A * 512)    // 131,072
#define PRE_BLOCKS ((TAB_UNITS + A_UNITS) / 256)   // 2464

__global__ __launch_bounds__(256) void prepass_kernel(
    const float* __restrict__ inputs, const float* __restrict__ lut,
    const float* __restrict__ cq, const float* __restrict__ cqb,
    u16* __restrict__ tabt, u16* __restrict__ at, float* __restrict__ S)
{
    const int u = blockIdx.x * 256 + threadIdx.x;
    if (u < SUMS_FLOATS) S[u] = 0.f;

    if (u < TAB_UNITS) {
        const int tile = u >> 9, v = u & 511;
        const int kk = v >> 6, q = (v >> 4) & 3, col = v & 15;
        const int cg = tile * 16 + col;
        bf16x8 r = {0, 0, 0, 0, 0, 0, 0, 0};
        if (cg < NTOT) {
            const float* src = table_row(cg, lut, cq, cqb) + kk * 32 + q * 8;
            const f32x4 lo = *(const f32x4*)src;
            const f32x4 hi = *(const f32x4*)(src + 4);
            r = bf16x8{ f2bf(lo[0]), f2bf(lo[1]), f2bf(lo[2]), f2bf(lo[3]),
                        f2bf(hi[0]), f2bf(hi[1]), f2bf(hi[2]), f2bf(hi[3]) };
        }
        *(bf16x8*)(tabt + (size_t)u * 8) = r;
    } else {
        const int ua = u - TAB_UNITS;
        const int tile = ua >> 9, v = ua & 511;
        const int kk = v >> 6, q = (v >> 4) & 3, row = v & 15;
        const float* src = inputs + (size_t)(tile * 16 + row) * FEAT + kk * 32 + q * 8;
        const f32x4 lo = *(const f32x4*)src;
        const f32x4 hi = *(const f32x4*)(src + 4);
        bf16x8 r = { f2bf(lo[0]), f2bf(lo[1]), f2bf(lo[2]), f2bf(lo[3]),
                     f2bf(hi[0]), f2bf(hi[1]), f2bf(hi[2]), f2bf(hi[3]) };
        *(bf16x8*)(at + (size_t)ua * 8) = r;
    }
}

// -------- Stage 1: fused GEMM + exp-sum + per-rowchunk finalize ------------
// 976 blocks (16 rowchunks x 61 colchunks), XCD-swizzled. LDS-shared B,
// double-buffered, ONE barrier/tile, 2-tile-deep register prefetch with
// STATICALLY-NAMED register pairs (ra*/rb*) and a manually 2x-unrolled tile
// loop -- dynamic indexing of a register array (r10's rg[sel]) spills to
// scratch and cost 9x. The LAST block of each rowchunk (ticket) finalizes
// its 256 rows inline; a 16-way global ticket publishes the two scalars.
__global__ __launch_bounds__(256, 2) void score_bf16_kernel(
    const u16* __restrict__ tabt, const u16* __restrict__ at,
    const int* __restrict__ roi, float* __restrict__ S,
    float* __restrict__ out)
{
    __shared__ __align__(16) short lbuf0[TILE_SH];
    __shared__ __align__(16) short lbuf1[TILE_SH];
    __shared__ float red[12];
    __shared__ u32 sflag;

    float* sum_bg = S;
    float* sum_nb = S + BATCH;
    float* acc    = S + 2 * BATCH;                 // det, oim, nv
    u32*   gt     = (u32*)(S + 2 * BATCH + 3);
    u32*   rct    = (u32*)(S + 2 * BATCH + 4);     // [16]

    const int lid = blockIdx.x;
    const int x8  = lid & 7;
    const int j   = lid >> 3;                 // [0, 122)
    const int rowchunk = x8 * 2 + (j & 1);    // [0, 16)
    const int colchunk = j >> 1;              // [0, 61)

    const int tid  = threadIdx.x;
    const int wave = tid >> 6;
    const int lane = tid & 63;
    const int l15  = lane & 15;
    const int quad = lane >> 4;

    // A fragments: 4 row-tiles, coalesced 1 KB/wave reads.
    bf16x8 af[4][8];
    {
        const u16* ab = at + (size_t)(rowchunk * 16 + wave * 4) * TILE_SH
                           + quad * 128 + l15 * 8;
        #pragma unroll
        for (int s = 0; s < 4; ++s)
            #pragma unroll
            for (int kk = 0; kk < 8; ++kk)
                af[s][kk] = *(const bf16x8*)(ab + (size_t)s * TILE_SH + kk * 512);
    }

    float pbg[16], pnb[16];
    #pragma unroll
    for (int i = 0; i < 16; ++i) { pbg[i] = 0.f; pnb[i] = 0.f; }

    const int bt0  = colchunk * 16;
    // colchunk 60: tiles 971..975 are zero-pad; tile 971 is run (masked to 0
    // by okc) so tmax stays even for the 2x-unrolled pipeline; 972+ skipped.
    const int tmax = (colchunk == 60) ? 12 : 16;

    auto loadg = [&](int bt, bf16x8& a, bf16x8& b) {
        const u16* g = tabt + (size_t)bt * TILE_SH;
        a = *(const bf16x8*)(g + tid * 8);
        b = *(const bf16x8*)(g + 2048 + tid * 8);
    };
    auto consume = [&](const short* lb, int bt) {
        f32x4 cc[4];
        #pragma unroll
        for (int s = 0; s < 4; ++s) cc[s] = f32x4{0.f, 0.f, 0.f, 0.f};
        #pragma unroll
        for (int kk = 0; kk < 8; ++kk) {
            const bf16x8 b = *(const bf16x8*)(lb + kk * 512 + quad * 128 + l15 * 8);
            cc[0] = __builtin_amdgcn_mfma_f32_16x16x32_bf16(af[0][kk], b, cc[0], 0, 0, 0);
            cc[1] = __builtin_amdgcn_mfma_f32_16x16x32_bf16(af[1][kk], b, cc[1], 0, 0, 0);
            cc[2] = __builtin_amdgcn_mfma_f32_16x16x32_bf16(af[2][kk], b, cc[2], 0, 0, 0);
            cc[3] = __builtin_amdgcn_mfma_f32_16x16x32_bf16(af[3][kk], b, cc[3], 0, 0, 0);
        }
        if (colchunk != 60) {
            if (bt < 312) {                    // all background
                #pragma unroll
                for (int s = 0; s < 4; ++s)
                    #pragma unroll
                    for (int r = 0; r < 4; ++r)
                        pbg[s * 4 + r] += exp2f(cc[s][r] * SCALE_LOG2E);
            } else if (bt > 312) {             // all non-bg
                #pragma unroll
                for (int s = 0; s < 4; ++s)
                    #pragma unroll
                    for (int r = 0; r < 4; ++r)
                        pnb[s * 4 + r] += exp2f(cc[s][r] * SCALE_LOG2E);
            } else {                           // tile 312: cols 4992..5007
                const bool isbg = l15 < 8;
                #pragma unroll
                for (int s = 0; s < 4; ++s)
                    #pragma unroll
                    for (int r = 0; r < 4; ++r) {
                        const float e = exp2f(cc[s][r] * SCALE_LOG2E);
                        pbg[s * 4 + r] += isbg ? e : 0.f;
                        pnb[s * 4 + r] += isbg ? 0.f : e;
                    }
            }
        } else {                               // last chunk: mask pad cols
            const bool okc = (bt * 16 + l15) < NTOT;
            #pragma unroll
            for (int s = 0; s < 4; ++s)
                #pragma unroll
                for (int r = 0; r < 4; ++r) {
                    const float e = exp2f(cc[s][r] * SCALE_LOG2E);
                    pnb[s * 4 + r] += okc ? e : 0.f;
                }
        }
    };

    // 2-deep pipeline, named registers only.
    bf16x8 ra0, ra1, rb0, rb1;
    loadg(bt0, ra0, ra1);
    loadg(bt0 + 1, rb0, rb1);

    #pragma unroll 1
    for (int tp = 0; tp < tmax; tp += 2) {
        // even tile -> lbuf0
        *(bf16x8*)(lbuf0 + tid * 8) = ra0;
        *(bf16x8*)(lbuf0 + 2048 + tid * 8) = ra1;
        if (tp + 2 < tmax) loadg(bt0 + tp + 2, ra0, ra1);
        __syncthreads();
        consume(lbuf0, bt0 + tp);

        // odd tile -> lbuf1
        *(bf16x8*)(lbuf1 + tid * 8) = rb0;
        *(bf16x8*)(lbuf1 + 2048 + tid * 8) = rb1;
        if (tp + 3 < tmax) loadg(bt0 + tp + 3, rb0, rb1);
        __syncthreads();
        consume(lbuf1, bt0 + tp + 1);
    }

    #pragma unroll
    for (int off = 1; off < 16; off <<= 1) {
        #pragma unroll
        for (int i = 0; i < 16; ++i) {
            pbg[i] += __shfl_xor(pbg[i], off);
            pnb[i] += __shfl_xor(pnb[i], off);
        }
    }
    if (l15 == 0) {
        #pragma unroll
        for (int s = 0; s < 4; ++s) {
            #pragma unroll
            for (int r = 0; r < 4; ++r) {
                const int row = (rowchunk * 16 + wave * 4 + s) * 16 + quad * 4 + r;
                atomic_add_f(&sum_bg[row], pbg[s * 4 + r]);
                atomic_add_f(&sum_nb[row], pnb[s * 4 + r]);
            }
        }
    }

    // ---- per-rowchunk ticket: last of 61 blocks finalizes its 256 rows ----
    __syncthreads();                           // all waves' atomics issued
    if (tid == 0) {
        __threadfence();
        const u32 tt = __hip_atomic_fetch_add(&rct[rowchunk], 1u,
                                              __ATOMIC_ACQ_REL, __HIP_MEMORY_SCOPE_AGENT);
        sflag = (tt == 60) ? 1u : 0u;
    }
    __syncthreads();
    if (sflag) {
        const int row = rowchunk * 256 + tid;
        const int r   = roi[row];

        // dot(inputs[row], lut[clamp(r)]) from the bf16 tiled buffers
        // (identical quantization to the GEMM).
        const int lr = NBG + (r < 0 ? 0 : r);
        const u16* arow = at   + (size_t)(row >> 4) * TILE_SH + (row & 15) * 8;
        const u16* brow = tabt + (size_t)(lr  >> 4) * TILE_SH + (lr  & 15) * 8;
        float dot = 0.f;
        #pragma unroll 4
        for (int c = 0; c < 32; ++c) {         // c = kk*4 + q
            const bf16x8 av = *(const bf16x8*)(arow + c * 128);
            const bf16x8 bv = *(const bf16x8*)(brow + c * 128);
            #pragma unroll
            for (int jj = 0; jj < 8; ++jj)
                dot += bf2f((u16)av[jj]) * bf2f((u16)bv[jj]);
        }

        const float sbg = atomic_ld_f(&sum_bg[row]);
        const float snb = atomic_ld_f(&sum_nb[row]);
        const float inv = 1.f / (sbg + snb);
        const float cls0 = sbg * inv;
        const float cls1 = snb * inv;
        out[2 * row]     = cls0;
        out[2 * row + 1] = cls1;

        const float cs = (r >= -1) ? cls1 : cls0;
        const float om = 1.f - cs;
        float det_c = -(0.25f * om * om * logf(cs)) * (1.f / (float)BATCH);
        float nv_c  = (r >= -1) ? 1.f : 0.f;
        float oim_c = 0.f;
        if (r >= 0) {
            const float logp = 30.f * dot - logf(snb);
            const float p    = expf(logp);
            const float om2  = 1.f - p;
            oim_c = -(0.25f * om2 * om2 * logp) * cls1 * cls1;
        }

        #pragma unroll
        for (int off = 32; off > 0; off >>= 1) {
            det_c += __shfl_xor(det_c, off);
            oim_c += __shfl_xor(oim_c, off);
            nv_c  += __shfl_xor(nv_c,  off);
        }
        if (lane == 0) { red[wave*3] = det_c; red[wave*3+1] = oim_c; red[wave*3+2] = nv_c; }
        __syncthreads();
        if (tid == 0) {
            atomic_add_f(&acc[0], red[0] + red[3] + red[6] + red[9]);
            atomic_add_f(&acc[1], red[1] + red[4] + red[7] + red[10]);
            atomic_add_f(&acc[2], red[2] + red[5] + red[8] + red[11]);
            __threadfence();
            const u32 g = __hip_atomic_fetch_add(gt, 1u, __ATOMIC_ACQ_REL,
                                                 __HIP_MEMORY_SCOPE_AGENT);
            if (g == 15) {
                const float det = atomic_ld_f(&acc[0]);
                const float oim = atomic_ld_f(&acc[1]);
                float nv        = atomic_ld_f(&acc[2]);
                if (nv < 1.f) nv = 1.f;
                out[2 * BATCH]     = det;
                out[2 * BATCH + 1] = oim / nv;
            }
        }
    }
}

// -------- f32 fallback path (round-4 structure + separate finalize) --------
__global__ __launch_bounds__(256, 2) void score_f32_kernel(
    const float* __restrict__ inputs, const float* __restrict__ lut,
    const float* __restrict__ cq, const float* __restrict__ cqb,
    float* __restrict__ sum_bg, float* __restrict__ sum_nb)
{
    __shared__ __align__(16) short lds[32 * LPITCH];
    const int wave = threadIdx.x >> 6;
    const int lane = threadIdx.x & 63;
    const int l15  = lane & 15;
    const int quad = lane >> 4;
    const int rowbase = blockIdx.y * 256;
    const int colbase = blockIdx.x * 256;

    bf16x8 afrag[4][8];
    #pragma unroll 1
    for (int c = 0; c < 8; ++c) {
        __syncthreads();
        #pragma unroll
        for (int i = 0; i < 8; ++i) {
            const int lr = i * 4 + wave;
            const f32x4 v = *(const f32x4*)(inputs + (size_t)(rowbase + c * 32 + lr) * FEAT + lane * 4);
            bf16x4 h = { f2bf(v[0]), f2bf(v[1]), f2bf(v[2]), f2bf(v[3]) };
            *(bf16x4*)(&lds[lr * LPITCH + lane * 4]) = h;
        }
        __syncthreads();
        if ((c >> 1) == wave) {
            const int half = c & 1;
            #pragma unroll
            for (int j2 = 0; j2 < 2; ++j2) {
                const int lr = j2 * 16 + l15;
                #pragma unroll
                for (int kk = 0; kk < 8; ++kk)
                    afrag[half * 2 + j2][kk] =
                        *(const bf16x8*)(&lds[lr * LPITCH + kk * 32 + quad * 8]);
            }
        }
    }

    float pbg[16], pnb[16];
    #pragma unroll
    for (int i = 0; i < 16; ++i) { pbg[i] = 0.f; pnb[i] = 0.f; }

    #pragma unroll 1
    for (int s = 0; s < 8; ++s) {
        __syncthreads();
        #pragma unroll
        for (int i = 0; i < 8; ++i) {
            const int lc = i * 4 + wave;
            const f32x4 v = *(const f32x4*)(table_row(colbase + s * 32 + lc, lut, cq, cqb) + lane * 4);
            bf16x4 h = { f2bf(v[0]), f2bf(v[1]), f2bf(v[2]), f2bf(v[3]) };
            *(bf16x4*)(&lds[lc * LPITCH + lane * 4]) = h;
        }
        __syncthreads();

        #pragma unroll
        for (int st = 0; st < 2; ++st) {
            const int lc = st * 16 + l15;
            f32x4 cc[4];
            #pragma unroll
            for (int q = 0; q < 4; ++q) cc[q] = f32x4{0.f, 0.f, 0.f, 0.f};
            #pragma unroll
            for (int kk = 0; kk < 8; ++kk) {
                const bf16x8 b = *(const bf16x8*)(&lds[lc * LPITCH + kk * 32 + quad * 8]);
                cc[0] = __builtin_amdgcn_mfma_f32_16x16x32_bf16(afrag[0][kk], b, cc[0], 0, 0, 0);
                cc[1] = __builtin_amdgcn_mfma_f32_16x16x32_bf16(afrag[1][kk], b, cc[1], 0, 0, 0);
                cc[2] = __builtin_amdgcn_mfma_f32_16x16x32_bf16(afrag[2][kk], b, cc[2], 0, 0, 0);
                cc[3] = __builtin_amdgcn_mfma_f32_16x16x32_bf16(afrag[3][kk], b, cc[3], 0, 0, 0);
            }
            const int n = colbase + s * 32 + st * 16 + l15;
            const bool okc  = n < NTOT;
            const bool isbg = n < NBG;
            #pragma unroll
            for (int q = 0; q < 4; ++q) {
                #pragma unroll
                for (int r = 0; r < 4; ++r) {
                    float e = exp2f(cc[q][r] * SCALE_LOG2E);
                    e = okc ? e : 0.f;
                    pbg[q * 4 + r] += isbg ? e : 0.f;
                    pnb[q * 4 + r] += isbg ? 0.f : e;
                }
            }
        }
    }

    #pragma unroll
    for (int off = 1; off < 16; off <<= 1) {
        #pragma unroll
        for (int i = 0; i < 16; ++i) {
            pbg[i] += __shfl_xor(pbg[i], off);
            pnb[i] += __shfl_xor(pnb[i], off);
        }
    }
    if (l15 == 0) {
        #pragma unroll
        for (int q = 0; q < 4; ++q) {
            #pragma unroll
            for (int r = 0; r < 4; ++r) {
                const int row = rowbase + wave * 64 + q * 16 + quad * 4 + r;
                atomic_add_f(&sum_bg[row], pbg[q * 4 + r]);
                atomic_add_f(&sum_nb[row], pnb[q * 4 + r]);
            }
        }
    }
}

__global__ __launch_bounds__(256) void finalize_kernel(
    const float* __restrict__ inputs, const int* __restrict__ roi_label,
    const float* __restrict__ lut,
    const float* __restrict__ sum_bg, const float* __restrict__ sum_nb,
    float* __restrict__ accums, unsigned int* __restrict__ ticket,
    float* __restrict__ out)
{
    __shared__ float s_det[4], s_oim[4], s_nv[4];
    const int wid  = threadIdx.x >> 6;
    const int lane = threadIdx.x & 63;

    float det_a = 0.f, oim_a = 0.f, nv_a = 0.f;

    #pragma unroll 1
    for (int it = 0; it < 8; ++it) {
        const int row = blockIdx.x * 32 + wid * 8 + it;
        const int r   = roi_label[row];

        float dot = 0.f;
        {
            const int rc = r < 0 ? 0 : r;
            const f32x4 xi = *(const f32x4*)(inputs + (size_t)row * FEAT + lane * 4);
            const f32x4 li = *(const f32x4*)(lut + (size_t)rc * FEAT + lane * 4);
            #pragma unroll
            for (int jj = 0; jj < 4; ++jj)
                dot += bf2f((u16)f2bf(xi[jj])) * bf2f((u16)f2bf(li[jj]));
        }
        #pragma unroll
        for (int off = 32; off > 0; off >>= 1) dot += __shfl_xor(dot, off);

        if (lane == 0) {
            const float sbg = sum_bg[row];
            const float snb = sum_nb[row];
            const float inv = 1.f / (sbg + snb);
            const float cls0 = sbg * inv;
            const float cls1 = snb * inv;
            out[2 * row]     = cls0;
            out[2 * row + 1] = cls1;

            const float cs = (r >= -1) ? cls1 : cls0;
            const float om = 1.f - cs;
            det_a += -(0.25f * om * om * logf(cs)) * (1.f / (float)BATCH);
            nv_a  += (r >= -1) ? 1.f : 0.f;

            if (r >= 0) {
                const float logp = 30.f * dot - logf(snb);
                const float p    = expf(logp);
                const float om2  = 1.f - p;
                oim_a += -(0.25f * om2 * om2 * logp) * cls1 * cls1;
            }
        }
    }

    if (lane == 0) { s_det[wid] = det_a; s_oim[wid] = oim_a; s_nv[wid] = nv_a; }
    __syncthreads();
    if (threadIdx.x == 0) {
        atomic_add_f(&accums[0], s_det[0] + s_det[1] + s_det[2] + s_det[3]);
        atomic_add_f(&accums[1], s_oim[0] + s_oim[1] + s_oim[2] + s_oim[3]);
        atomic_add_f(&accums[2], s_nv[0] + s_nv[1] + s_nv[2] + s_nv[3]);
        __threadfence();
        const unsigned t = __hip_atomic_fetch_add(ticket, 1u, __ATOMIC_ACQ_REL,
                                                  __HIP_MEMORY_SCOPE_AGENT);
        if (t == gridDim.x - 1) {
            const float det = atomic_ld_f(&accums[0]);
            const float oim = atomic_ld_f(&accums[1]);
            float nv        = atomic_ld_f(&accums[2]);
            if (nv < 1.f) nv = 1.f;
            out[2 * BATCH]     = det;
            out[2 * BATCH + 1] = oim / nv;
        }
    }
}

extern "C" void kernel_launch(void* const* d_in, const int* in_sizes, int n_in,
                              void* d_out, int out_size, void* d_ws, size_t ws_size,
                              hipStream_t stream)
{
    const float* inputs = (const float*)d_in[0];
    const int*   roi    = (const int*)d_in[1];
    const float* lut    = (const float*)d_in[2];
    const float* cq     = (const float*)d_in[3];
    const float* cqb    = (const float*)d_in[4];
    float* out = (float*)d_out;

    if (ws_size >= (size_t)WS_NEED) {
        u16* tabt = (u16*)d_ws;
        u16* at   = (u16*)((char*)d_ws + TABT_BYTES);
        float* S  = (float*)((char*)d_ws + SUMS_OFF);
        prepass_kernel<<<PRE_BLOCKS, 256, 0, stream>>>(inputs, lut, cq, cqb, tabt, at, S);
        score_bf16_kernel<<<976, 256, 0, stream>>>(tabt, at, roi, S, out);
    } else {
        float* S = (float*)d_ws;
        hipMemsetAsync(S, 0, SUMS_FLOATS * sizeof(float), stream);
        dim3 g1(61, 16);
        score_f32_kernel<<<g1, 256, 0, stream>>>(inputs, lut, cq, cqb, S, S + BATCH);
        finalize_kernel<<<128, 256, 0, stream>>>(
            inputs, roi, lut, S, S + BATCH, S + 2 * BATCH,
            (unsigned int*)(S + 2 * BATCH + 3), out);
    }
}

// Round 12
// 186.999 us; speedup vs baseline: 2.9132x; 1.0067x over previous
//
#include <hip/hip_runtime.h>
#include <hip/hip_bf16.h>

typedef unsigned short u16;
typedef unsigned int u32;
typedef __attribute__((ext_vector_type(8))) short bf16x8;   // 8 bf16 = 4 VGPRs
typedef __attribute__((ext_vector_type(4))) short bf16x4;
typedef __attribute__((ext_vector_type(4))) float f32x4;

#define NBG   5000
#define NPID  5532
#define NTOT  15532      // 5000 + 5532 + 5000
#define FEAT  256
#define BATCH 4096
#define SCALE_LOG2E 43.280851226668994f   // 30 * log2(e)
#define LPITCH 264       // f32-fallback LDS pitch (shorts)

#define NTILE_B  976             // 61 chunks x 16 tiles; 971 real, 5 zero-pad
#define TILE_SH  4096            // shorts per 16-col tile (16*256)
#define NTILE_A  256             // 4096 rows / 16

// ---- workspace layout (bytes) ----
#define TABT_BYTES ((size_t)NTILE_B * TILE_SH * 2)   // 7,995,392
#define AT_BYTES   ((size_t)NTILE_A * TILE_SH * 2)   // 2,097,152
#define SUMS_OFF   (TABT_BYTES + AT_BYTES)
// S floats: [0,4096) bg | [4096,8192) nb | 8192 det | 8193 oim | 8194 nv
//           | 8195 gticket(u32) | 8196..8211 rc_ticket[16](u32)
#define SUMS_FLOATS 8212
#define WS_NEED    (SUMS_OFF + SUMS_FLOATS * 4)

__device__ __forceinline__ void atomic_add_f(float* p, float v) {
    __hip_atomic_fetch_add(p, v, __ATOMIC_RELAXED, __HIP_MEMORY_SCOPE_AGENT);
}
__device__ __forceinline__ float atomic_ld_f(const float* p) {
    return __hip_atomic_load(p, __ATOMIC_RELAXED, __HIP_MEMORY_SCOPE_AGENT);
}
__device__ __forceinline__ short f2bf(float f) {
    return (short)__bfloat16_as_ushort(__float2bfloat16(f));
}
__device__ __forceinline__ float bf2f(u16 u) {
    union { u32 i; float f; } v; v.i = ((u32)u) << 16; return v.f;
}

__device__ __forceinline__ const float* table_row(
    int n, const float* __restrict__ lut, const float* __restrict__ cq,
    const float* __restrict__ cqb)
{
    const int nc = n < NTOT ? n : NTOT - 1;
    if (nc < NBG)        return cqb + (size_t)nc * FEAT;
    if (nc < NBG + NPID) return lut + (size_t)(nc - NBG) * FEAT;
    return cq + (size_t)(nc - NBG - NPID) * FEAT;
}

// -------- Stage 0: f32 -> bf16 tiled prepass, wave-per-row reads -----------
// Tile layout (8192 B): short off = kk*512 + q*128 + col*8 (+sub), holding
// src[col][kk*32 + q*8 .. +8].  One block per 16-row tile; pass p: the
// wave covers exactly ONE source row (64 lanes x 16 B = 1 KB, perfectly
// coalesced read); scattered 8-B writes are fire-and-forget through L2.
#define PRE_BLOCKS2 (NTILE_B + NTILE_A)   // 1232

__global__ __launch_bounds__(256) void prepass_kernel(
    const float* __restrict__ inputs, const float* __restrict__ lut,
    const float* __restrict__ cq, const float* __restrict__ cqb,
    u16* __restrict__ tabt, u16* __restrict__ at, float* __restrict__ S)
{
    const int b = blockIdx.x, tid = threadIdx.x;
    const int fid = b * 256 + tid;
    if (fid < SUMS_FLOATS) S[fid] = 0.f;

    const bool isA = (b >= NTILE_B);
    const int tile = isA ? (b - NTILE_B) : b;
    u16* dst = (isA ? at : tabt) + (size_t)tile * TILE_SH;

    #pragma unroll
    for (int p = 0; p < 4; ++p) {
        const int flat = p * 1024 + tid * 4;   // float index within 16x256 tile
        const int row  = flat >> 8;            // 0..15 (col within tile)
        const int pos  = flat & 255;           // float pos within row
        const int kk = pos >> 5, q = (pos >> 3) & 3, sub = pos & 7;  // sub in {0,4}
        f32x4 v;
        bool ok = true;
        if (isA) {
            v = *(const f32x4*)(inputs + (size_t)(tile * 16 + row) * FEAT + pos);
        } else {
            const int cg = tile * 16 + row;
            ok = cg < NTOT;
            v = *(const f32x4*)(table_row(cg, lut, cq, cqb) + pos);
        }
        const bf16x4 h = ok ? bf16x4{ f2bf(v[0]), f2bf(v[1]), f2bf(v[2]), f2bf(v[3]) }
                            : bf16x4{ 0, 0, 0, 0 };
        *(bf16x4*)(dst + kk * 512 + q * 128 + row * 8 + sub) = h;
    }
}

// -------- Stage 1: fused GEMM + exp-sum + per-rowchunk finalize ------------
// 976 blocks (16 rowchunks x 61 colchunks), XCD-swizzled. LDS-shared B,
// double-buffered, ONE barrier/tile. Pipeline order per tile:
//   ds_write(t) [vmcnt-waits load(t)]; barrier [vmcnt already 0 -> cheap];
//   issue load(t+1); consume(t) overlaps load(t+1).
// Staging uses ONLY r0,r1 (named; 16 VGPRs) -- r10/r11 showed deeper staging
// spills to scratch on the unified VGPR/AGPR file (af occupies 128).
__global__ __launch_bounds__(256, 2) void score_bf16_kernel(
    const u16* __restrict__ tabt, const u16* __restrict__ at,
    const int* __restrict__ roi, float* __restrict__ S,
    float* __restrict__ out)
{
    __shared__ __align__(16) short lbuf0[TILE_SH];
    __shared__ __align__(16) short lbuf1[TILE_SH];
    __shared__ float red[12];
    __shared__ u32 sflag;

    float* sum_bg = S;
    float* sum_nb = S + BATCH;
    float* acc    = S + 2 * BATCH;                 // det, oim, nv
    u32*   gt     = (u32*)(S + 2 * BATCH + 3);
    u32*   rct    = (u32*)(S + 2 * BATCH + 4);     // [16]

    const int lid = blockIdx.x;
    const int x8  = lid & 7;
    const int j   = lid >> 3;                 // [0, 122)
    const int rowchunk = x8 * 2 + (j & 1);    // [0, 16)
    const int colchunk = j >> 1;              // [0, 61)

    const int tid  = threadIdx.x;
    const int wave = tid >> 6;
    const int lane = tid & 63;
    const int l15  = lane & 15;
    const int quad = lane >> 4;

    // A fragments: 4 row-tiles, coalesced 1 KB/wave reads.
    bf16x8 af[4][8];
    {
        const u16* ab = at + (size_t)(rowchunk * 16 + wave * 4) * TILE_SH
                           + quad * 128 + l15 * 8;
        #pragma unroll
        for (int s = 0; s < 4; ++s)
            #pragma unroll
            for (int kk = 0; kk < 8; ++kk)
                af[s][kk] = *(const bf16x8*)(ab + (size_t)s * TILE_SH + kk * 512);
    }

    float pbg[16], pnb[16];
    #pragma unroll
    for (int i = 0; i < 16; ++i) { pbg[i] = 0.f; pnb[i] = 0.f; }

    const int bt0  = colchunk * 16;
    // colchunk 60: tiles 971..975 are zero-pad; run 971 (zeros, okc-masked)
    // so tmax stays even; 972+ skipped.
    const int tmax = (colchunk == 60) ? 12 : 16;

    auto loadg = [&](int bt, bf16x8& a, bf16x8& b) {
        const u16* g = tabt + (size_t)bt * TILE_SH;
        a = *(const bf16x8*)(g + tid * 8);
        b = *(const bf16x8*)(g + 2048 + tid * 8);
    };
    auto consume = [&](const short* lb, int bt) {
        f32x4 cc[4];
        #pragma unroll
        for (int s = 0; s < 4; ++s) cc[s] = f32x4{0.f, 0.f, 0.f, 0.f};
        #pragma unroll
        for (int kk = 0; kk < 8; ++kk) {
            const bf16x8 b = *(const bf16x8*)(lb + kk * 512 + quad * 128 + l15 * 8);
            cc[0] = __builtin_amdgcn_mfma_f32_16x16x32_bf16(af[0][kk], b, cc[0], 0, 0, 0);
            cc[1] = __builtin_amdgcn_mfma_f32_16x16x32_bf16(af[1][kk], b, cc[1], 0, 0, 0);
            cc[2] = __builtin_amdgcn_mfma_f32_16x16x32_bf16(af[2][kk], b, cc[2], 0, 0, 0);
            cc[3] = __builtin_amdgcn_mfma_f32_16x16x32_bf16(af[3][kk], b, cc[3], 0, 0, 0);
        }
        if (colchunk != 60) {
            if (bt < 312) {                    // all background
                #pragma unroll
                for (int s = 0; s < 4; ++s)
                    #pragma unroll
                    for (int r = 0; r < 4; ++r)
                        pbg[s * 4 + r] += exp2f(cc[s][r] * SCALE_LOG2E);
            } else if (bt > 312) {             // all non-bg
                #pragma unroll
                for (int s = 0; s < 4; ++s)
                    #pragma unroll
                    for (int r = 0; r < 4; ++r)
                        pnb[s * 4 + r] += exp2f(cc[s][r] * SCALE_LOG2E);
            } else {                           // tile 312: cols 4992..5007
                const bool isbg = l15 < 8;
                #pragma unroll
                for (int s = 0; s < 4; ++s)
                    #pragma unroll
                    for (int r = 0; r < 4; ++r) {
                        const float e = exp2f(cc[s][r] * SCALE_LOG2E);
                        pbg[s * 4 + r] += isbg ? e : 0.f;
                        pnb[s * 4 + r] += isbg ? 0.f : e;
                    }
            }
        } else {                               // last chunk: mask pad cols
            const bool okc = (bt * 16 + l15) < NTOT;
            #pragma unroll
            for (int s = 0; s < 4; ++s)
                #pragma unroll
                for (int r = 0; r < 4; ++r) {
                    const float e = exp2f(cc[s][r] * SCALE_LOG2E);
                    pnb[s * 4 + r] += okc ? e : 0.f;
                }
        }
    };

    bf16x8 r0, r1;
    loadg(bt0, r0, r1);

    #pragma unroll 1
    for (int tp = 0; tp < tmax; tp += 2) {
        // even tile -> lbuf0
        *(bf16x8*)(lbuf0 + tid * 8) = r0;
        *(bf16x8*)(lbuf0 + 2048 + tid * 8) = r1;
        __syncthreads();
        if (tp + 1 < tmax) loadg(bt0 + tp + 1, r0, r1);
        consume(lbuf0, bt0 + tp);

        // odd tile -> lbuf1
        *(bf16x8*)(lbuf1 + tid * 8) = r0;
        *(bf16x8*)(lbuf1 + 2048 + tid * 8) = r1;
        __syncthreads();
        if (tp + 2 < tmax) loadg(bt0 + tp + 2, r0, r1);
        consume(lbuf1, bt0 + tp + 1);
    }

    #pragma unroll
    for (int off = 1; off < 16; off <<= 1) {
        #pragma unroll
        for (int i = 0; i < 16; ++i) {
            pbg[i] += __shfl_xor(pbg[i], off);
            pnb[i] += __shfl_xor(pnb[i], off);
        }
    }
    if (l15 == 0) {
        #pragma unroll
        for (int s = 0; s < 4; ++s) {
            #pragma unroll
            for (int r = 0; r < 4; ++r) {
                const int row = (rowchunk * 16 + wave * 4 + s) * 16 + quad * 4 + r;
                atomic_add_f(&sum_bg[row], pbg[s * 4 + r]);
                atomic_add_f(&sum_nb[row], pnb[s * 4 + r]);
            }
        }
    }

    // ---- per-rowchunk ticket: last of 61 blocks finalizes its 256 rows ----
    __syncthreads();                           // all waves' atomics issued
    if (tid == 0) {
        __threadfence();
        const u32 tt = __hip_atomic_fetch_add(&rct[rowchunk], 1u,
                                              __ATOMIC_ACQ_REL, __HIP_MEMORY_SCOPE_AGENT);
        sflag = (tt == 60) ? 1u : 0u;
    }
    __syncthreads();
    if (sflag) {
        const int row = rowchunk * 256 + tid;
        const int r   = roi[row];

        // dot(inputs[row], lut[clamp(r)]) from the bf16 tiled buffers
        // (identical quantization to the GEMM).
        const int lr = NBG + (r < 0 ? 0 : r);
        const u16* arow = at   + (size_t)(row >> 4) * TILE_SH + (row & 15) * 8;
        const u16* brow = tabt + (size_t)(lr  >> 4) * TILE_SH + (lr  & 15) * 8;
        float dot = 0.f;
        #pragma unroll 4
        for (int c = 0; c < 32; ++c) {         // c = kk*4 + q
            const bf16x8 av = *(const bf16x8*)(arow + c * 128);
            const bf16x8 bv = *(const bf16x8*)(brow + c * 128);
            #pragma unroll
            for (int jj = 0; jj < 8; ++jj)
                dot += bf2f((u16)av[jj]) * bf2f((u16)bv[jj]);
        }

        const float sbg = atomic_ld_f(&sum_bg[row]);
        const float snb = atomic_ld_f(&sum_nb[row]);
        const float inv = 1.f / (sbg + snb);
        const float cls0 = sbg * inv;
        const float cls1 = snb * inv;
        out[2 * row]     = cls0;
        out[2 * row + 1] = cls1;

        const float cs = (r >= -1) ? cls1 : cls0;
        const float om = 1.f - cs;
        float det_c = -(0.25f * om * om * logf(cs)) * (1.f / (float)BATCH);
        float nv_c  = (r >= -1) ? 1.f : 0.f;
        float oim_c = 0.f;
        if (r >= 0) {
            const float logp = 30.f * dot - logf(snb);
            const float p    = expf(logp);
            const float om2  = 1.f - p;
            oim_c = -(0.25f * om2 * om2 * logp) * cls1 * cls1;
        }

        #pragma unroll
        for (int off = 32; off > 0; off >>= 1) {
            det_c += __shfl_xor(det_c, off);
            oim_c += __shfl_xor(oim_c, off);
            nv_c  += __shfl_xor(nv_c,  off);
        }
        if (lane == 0) { red[wave*3] = det_c; red[wave*3+1] = oim_c; red[wave*3+2] = nv_c; }
        __syncthreads();
        if (tid == 0) {
            atomic_add_f(&acc[0], red[0] + red[3] + red[6] + red[9]);
            atomic_add_f(&acc[1], red[1] + red[4] + red[7] + red[10]);
            atomic_add_f(&acc[2], red[2] + red[5] + red[8] + red[11]);
            __threadfence();
            const u32 g = __hip_atomic_fetch_add(gt, 1u, __ATOMIC_ACQ_REL,
                                                 __HIP_MEMORY_SCOPE_AGENT);
            if (g == 15) {
                const float det = atomic_ld_f(&acc[0]);
                const float oim = atomic_ld_f(&acc[1]);
                float nv        = atomic_ld_f(&acc[2]);
                if (nv < 1.f) nv = 1.f;
                out[2 * BATCH]     = det;
                out[2 * BATCH + 1] = oim / nv;
            }
        }
    }
}

// -------- f32 fallback path (round-4 structure + separate finalize) --------
__global__ __launch_bounds__(256, 2) void score_f32_kernel(
    const float* __restrict__ inputs, const float* __restrict__ lut,
    const float* __restrict__ cq, const float* __restrict__ cqb,
    float* __restrict__ sum_bg, float* __restrict__ sum_nb)
{
    __shared__ __align__(16) short lds[32 * LPITCH];
    const int wave = threadIdx.x >> 6;
    const int lane = threadIdx.x & 63;
    const int l15  = lane & 15;
    const int quad = lane >> 4;
    const int rowbase = blockIdx.y * 256;
    const int colbase = blockIdx.x * 256;

    bf16x8 afrag[4][8];
    #pragma unroll 1
    for (int c = 0; c < 8; ++c) {
        __syncthreads();
        #pragma unroll
        for (int i = 0; i < 8; ++i) {
            const int lr = i * 4 + wave;
            const f32x4 v = *(const f32x4*)(inputs + (size_t)(rowbase + c * 32 + lr) * FEAT + lane * 4);
            bf16x4 h = { f2bf(v[0]), f2bf(v[1]), f2bf(v[2]), f2bf(v[3]) };
            *(bf16x4*)(&lds[lr * LPITCH + lane * 4]) = h;
        }
        __syncthreads();
        if ((c >> 1) == wave) {
            const int half = c & 1;
            #pragma unroll
            for (int j2 = 0; j2 < 2; ++j2) {
                const int lr = j2 * 16 + l15;
                #pragma unroll
                for (int kk = 0; kk < 8; ++kk)
                    afrag[half * 2 + j2][kk] =
                        *(const bf16x8*)(&lds[lr * LPITCH + kk * 32 + quad * 8]);
            }
        }
    }

    float pbg[16], pnb[16];
    #pragma unroll
    for (int i = 0; i < 16; ++i) { pbg[i] = 0.f; pnb[i] = 0.f; }

    #pragma unroll 1
    for (int s = 0; s < 8; ++s) {
        __syncthreads();
        #pragma unroll
        for (int i = 0; i < 8; ++i) {
            const int lc = i * 4 + wave;
            const f32x4 v = *(const f32x4*)(table_row(colbase + s * 32 + lc, lut, cq, cqb) + lane * 4);
            bf16x4 h = { f2bf(v[0]), f2bf(v[1]), f2bf(v[2]), f2bf(v[3]) };
            *(bf16x4*)(&lds[lc * LPITCH + lane * 4]) = h;
        }
        __syncthreads();

        #pragma unroll
        for (int st = 0; st < 2; ++st) {
            const int lc = st * 16 + l15;
            f32x4 cc[4];
            #pragma unroll
            for (int q = 0; q < 4; ++q) cc[q] = f32x4{0.f, 0.f, 0.f, 0.f};
            #pragma unroll
            for (int kk = 0; kk < 8; ++kk) {
                const bf16x8 b = *(const bf16x8*)(&lds[lc * LPITCH + kk * 32 + quad * 8]);
                cc[0] = __builtin_amdgcn_mfma_f32_16x16x32_bf16(afrag[0][kk], b, cc[0], 0, 0, 0);
                cc[1] = __builtin_amdgcn_mfma_f32_16x16x32_bf16(afrag[1][kk], b, cc[1], 0, 0, 0);
                cc[2] = __builtin_amdgcn_mfma_f32_16x16x32_bf16(afrag[2][kk], b, cc[2], 0, 0, 0);
                cc[3] = __builtin_amdgcn_mfma_f32_16x16x32_bf16(afrag[3][kk], b, cc[3], 0, 0, 0);
            }
            const int n = colbase + s * 32 + st * 16 + l15;
            const bool okc  = n < NTOT;
            const bool isbg = n < NBG;
            #pragma unroll
            for (int q = 0; q < 4; ++q) {
                #pragma unroll
                for (int r = 0; r < 4; ++r) {
                    float e = exp2f(cc[q][r] * SCALE_LOG2E);
                    e = okc ? e : 0.f;
                    pbg[q * 4 + r] += isbg ? e : 0.f;
                    pnb[q * 4 + r] += isbg ? 0.f : e;
                }
            }
        }
    }

    #pragma unroll
    for (int off = 1; off < 16; off <<= 1) {
        #pragma unroll
        for (int i = 0; i < 16; ++i) {
            pbg[i] += __shfl_xor(pbg[i], off);
            pnb[i] += __shfl_xor(pnb[i], off);
        }
    }
    if (l15 == 0) {
        #pragma unroll
        for (int q = 0; q < 4; ++q) {
            #pragma unroll
            for (int r = 0; r < 4; ++r) {
                const int row = rowbase + wave * 64 + q * 16 + quad * 4 + r;
                atomic_add_f(&sum_bg[row], pbg[q * 4 + r]);
                atomic_add_f(&sum_nb[row], pnb[q * 4 + r]);
            }
        }
    }
}

__global__ __launch_bounds__(256) void finalize_kernel(
    const float* __restrict__ inputs, const int* __restrict__ roi_label,
    const float* __restrict__ lut,
    const float* __restrict__ sum_bg, const float* __restrict__ sum_nb,
    float* __restrict__ accums, unsigned int* __restrict__ ticket,
    float* __restrict__ out)
{
    __shared__ float s_det[4], s_oim[4], s_nv[4];
    const int wid  = threadIdx.x >> 6;
    const int lane = threadIdx.x & 63;

    float det_a = 0.f, oim_a = 0.f, nv_a = 0.f;

    #pragma unroll 1
    for (int it = 0; it < 8; ++it) {
        const int row = blockIdx.x * 32 + wid * 8 + it;
        const int r   = roi_label[row];

        float dot = 0.f;
        {
            const int rc = r < 0 ? 0 : r;
            const f32x4 xi = *(const f32x4*)(inputs + (size_t)row * FEAT + lane * 4);
            const f32x4 li = *(const f32x4*)(lut + (size_t)rc * FEAT + lane * 4);
            #pragma unroll
            for (int jj = 0; jj < 4; ++jj)
                dot += bf2f((u16)f2bf(xi[jj])) * bf2f((u16)f2bf(li[jj]));
        }
        #pragma unroll
        for (int off = 32; off > 0; off >>= 1) dot += __shfl_xor(dot, off);

        if (lane == 0) {
            const float sbg = sum_bg[row];
            const float snb = sum_nb[row];
            const float inv = 1.f / (sbg + snb);
            const float cls0 = sbg * inv;
            const float cls1 = snb * inv;
            out[2 * row]     = cls0;
            out[2 * row + 1] = cls1;

            const float cs = (r >= -1) ? cls1 : cls0;
            const float om = 1.f - cs;
            det_a += -(0.25f * om * om * logf(cs)) * (1.f / (float)BATCH);
            nv_a  += (r >= -1) ? 1.f : 0.f;

            if (r >= 0) {
                const float logp = 30.f * dot - logf(snb);
                const float p    = expf(logp);
                const float om2  = 1.f - p;
                oim_a += -(0.25f * om2 * om2 * logp) * cls1 * cls1;
            }
        }
    }

    if (lane == 0) { s_det[wid] = det_a; s_oim[wid] = oim_a; s_nv[wid] = nv_a; }
    __syncthreads();
    if (threadIdx.x == 0) {
        atomic_add_f(&accums[0], s_det[0] + s_det[1] + s_det[2] + s_det[3]);
        atomic_add_f(&accums[1], s_oim[0] + s_oim[1] + s_oim[2] + s_oim[3]);
        atomic_add_f(&accums[2], s_nv[0] + s_nv[1] + s_nv[2] + s_nv[3]);
        __threadfence();
        const unsigned t = __hip_atomic_fetch_add(ticket, 1u, __ATOMIC_ACQ_REL,
                                                  __HIP_MEMORY_SCOPE_AGENT);
        if (t == gridDim.x - 1) {
            const float det = atomic_ld_f(&accums[0]);
            const float oim = atomic_ld_f(&accums[1]);
            float nv        = atomic_ld_f(&accums[2]);
            if (nv < 1.f) nv = 1.f;
            out[2 * BATCH]     = det;
            out[2 * BATCH + 1] = oim / nv;
        }
    }
}

extern "C" void kernel_launch(void* const* d_in, const int* in_sizes, int n_in,
                              void* d_out, int out_size, void* d_ws, size_t ws_size,
                              hipStream_t stream)
{
    const float* inputs = (const float*)d_in[0];
    const int*   roi    = (const int*)d_in[1];
    const float* lut    = (const float*)d_in[2];
    const float* cq     = (const float*)d_in[3];
    const float* cqb    = (const float*)d_in[4];
    float* out = (float*)d_out;

    if (ws_size >= (size_t)WS_NEED) {
        u16* tabt = (u16*)d_ws;
        u16* at   = (u16*)((char*)d_ws + TABT_BYTES);
        float* S  = (float*)((char*)d_ws + SUMS_OFF);
        prepass_kernel<<<PRE_BLOCKS2, 256, 0, stream>>>(inputs, lut, cq, cqb, tabt, at, S);
        score_bf16_kernel<<<976, 256, 0, stream>>>(tabt, at, roi, S, out);
    } else {
        float* S = (float*)d_ws;
        hipMemsetAsync(S, 0, SUMS_FLOATS * sizeof(float), stream);
        dim3 g1(61, 16);
        score_f32_kernel<<<g1, 256, 0, stream>>>(inputs, lut, cq, cqb, S, S + BATCH);
        finalize_kernel<<<128, 256, 0, stream>>>(
            inputs, roi, lut, S, S + BATCH, S + 2 * BATCH,
            (unsigned int*)(S + 2 * BATCH + 3), out);
    }
}

// Round 13
// 154.018 us; speedup vs baseline: 3.5371x; 1.2141x over previous
//
#include <hip/hip_runtime.h>
#include <hip/hip_bf16.h>

typedef unsigned short u16;
typedef unsigned int u32;
typedef __attribute__((ext_vector_type(8))) short bf16x8;   // 8 bf16 = 4 VGPRs
typedef __attribute__((ext_vector_type(4))) short bf16x4;
typedef __attribute__((ext_vector_type(4))) float f32x4;

#define NBG   5000
#define NPID  5532
#define NTOT  15532      // 5000 + 5532 + 5000
#define FEAT  256
#define BATCH 4096
#define SCALE_LOG2E 43.280851226668994f   // 30 * log2(e)
#define LPITCH 264       // f32-fallback LDS pitch (shorts)

#define NTILE_B  976             // 61 chunks x 16 tiles; 971 real, 5 zero-pad
#define TILE_SH  4096            // shorts per 16-col tile (16*256)
#define NTILE_A  256             // 4096 rows / 16

// ---- workspace layout (bytes) ----
#define TABT_BYTES ((size_t)NTILE_B * TILE_SH * 2)   // 7,995,392
#define AT_BYTES   ((size_t)NTILE_A * TILE_SH * 2)   // 2,097,152
#define SUMS_OFF   (TABT_BYTES + AT_BYTES)
// S floats: [0,4096) bg | [4096,8192) nb | 8192 det | 8193 oim | 8194 nv
//           | 8195 ticket(u32)
#define SUMS_FLOATS 8196
#define WS_NEED    (SUMS_OFF + SUMS_FLOATS * 4)

__device__ __forceinline__ void atomic_add_f(float* p, float v) {
    __hip_atomic_fetch_add(p, v, __ATOMIC_RELAXED, __HIP_MEMORY_SCOPE_AGENT);
}
__device__ __forceinline__ float atomic_ld_f(const float* p) {
    return __hip_atomic_load(p, __ATOMIC_RELAXED, __HIP_MEMORY_SCOPE_AGENT);
}
__device__ __forceinline__ short f2bf(float f) {
    return (short)__bfloat16_as_ushort(__float2bfloat16(f));
}
__device__ __forceinline__ float bf2f(u16 u) {
    union { u32 i; float f; } v; v.i = ((u32)u) << 16; return v.f;
}

__device__ __forceinline__ const float* table_row(
    int n, const float* __restrict__ lut, const float* __restrict__ cq,
    const float* __restrict__ cqb)
{
    const int nc = n < NTOT ? n : NTOT - 1;
    if (nc < NBG)        return cqb + (size_t)nc * FEAT;
    if (nc < NBG + NPID) return lut + (size_t)(nc - NBG) * FEAT;
    return cq + (size_t)(nc - NBG - NPID) * FEAT;
}

// -------- Stage 0: f32 -> bf16 tiled prepass via LDS transpose -------------
// Tile layout (8192 B): short off = kk*512 + q*128 + col*8 (+sub), holding
// src[col][kk*32 + q*8 .. +8].  Both global directions coalesced:
//  read: 16 threads cover one 1 KB source row (16 full lines/wave);
//  write: after LDS transpose, linear 8 KB block copy (2 KB/wave-inst).
// (r11's gather-read and r12's scatter-write were each one-sided -> both
//  prepasses were equally TA-bound at ~65 us.)
#define PRE_BLOCKS (NTILE_B + NTILE_A)   // 1232

__global__ __launch_bounds__(256) void prepass_kernel(
    const float* __restrict__ inputs, const float* __restrict__ lut,
    const float* __restrict__ cq, const float* __restrict__ cqb,
    u16* __restrict__ tabt, u16* __restrict__ at, float* __restrict__ S)
{
    __shared__ __align__(16) short tl[TILE_SH];
    const int b = blockIdx.x, tid = threadIdx.x;
    const int fid = b * 256 + tid;
    if (fid < SUMS_FLOATS) S[fid] = 0.f;

    const bool isA = (b >= NTILE_B);
    const int tile = isA ? (b - NTILE_B) : b;
    u16* dst = (isA ? at : tabt) + (size_t)tile * TILE_SH;

    const int row = tid >> 4;          // 0..15 (source row within tile)
    const int c16 = tid & 15;          // 16-float chunk within the row
    bool ok = true;
    const float* src;
    if (isA) {
        src = inputs + (size_t)(tile * 16 + row) * FEAT + c16 * 16;
    } else {
        const int cg = tile * 16 + row;
        ok = cg < NTOT;
        src = table_row(cg, lut, cq, cqb) + c16 * 16;
    }
    #pragma unroll
    for (int i = 0; i < 4; ++i) {
        const f32x4 v = *(const f32x4*)(src + i * 4);
        const int P = c16 * 16 + i * 4;                   // float pos in row
        const int kk = P >> 5, q = (P >> 3) & 3, sub = P & 7;   // sub in {0,4}
        const bf16x4 h = ok ? bf16x4{ f2bf(v[0]), f2bf(v[1]), f2bf(v[2]), f2bf(v[3]) }
                            : bf16x4{ 0, 0, 0, 0 };
        *(bf16x4*)(tl + kk * 512 + q * 128 + row * 8 + sub) = h;
    }
    __syncthreads();
    *(bf16x8*)(dst + tid * 8)        = *(const bf16x8*)(tl + tid * 8);
    *(bf16x8*)(dst + 2048 + tid * 8) = *(const bf16x8*)(tl + 2048 + tid * 8);
}

// -------- Stage 1: fused GEMM + exp-sum.  NO fences, NO tickets. -----------
// 976 blocks (16 rowchunks x 61 colchunks), XCD-swizzled. LDS-shared B,
// double-buffered, ONE barrier/tile:
//   ds_write(t); barrier; issue load(t+1); consume(t) overlaps load(t+1).
// Staging regs: ONLY r0,r1 (r11: deeper staging tips the unified VGPR/AGPR
// file into scratch).  r12 lesson: per-block agent fences (fused finalize)
// force L2 writebacks (+18 MB WRITE_SIZE) and invalidate sibling blocks'
// cached B -> finalize lives in its own small kernel again.
__global__ __launch_bounds__(256, 2) void score_bf16_kernel(
    const u16* __restrict__ tabt, const u16* __restrict__ at,
    float* __restrict__ sum_bg, float* __restrict__ sum_nb)
{
    __shared__ __align__(16) short lbuf0[TILE_SH];
    __shared__ __align__(16) short lbuf1[TILE_SH];

    const int lid = blockIdx.x;
    const int x8  = lid & 7;
    const int j   = lid >> 3;                 // [0, 122)
    const int rowchunk = x8 * 2 + (j & 1);    // [0, 16)
    const int colchunk = j >> 1;              // [0, 61)

    const int tid  = threadIdx.x;
    const int wave = tid >> 6;
    const int lane = tid & 63;
    const int l15  = lane & 15;
    const int quad = lane >> 4;

    // A fragments: 4 row-tiles, coalesced 1 KB/wave reads.
    bf16x8 af[4][8];
    {
        const u16* ab = at + (size_t)(rowchunk * 16 + wave * 4) * TILE_SH
                           + quad * 128 + l15 * 8;
        #pragma unroll
        for (int s = 0; s < 4; ++s)
            #pragma unroll
            for (int kk = 0; kk < 8; ++kk)
                af[s][kk] = *(const bf16x8*)(ab + (size_t)s * TILE_SH + kk * 512);
    }

    float pbg[16], pnb[16];
    #pragma unroll
    for (int i = 0; i < 16; ++i) { pbg[i] = 0.f; pnb[i] = 0.f; }

    const int bt0  = colchunk * 16;
    // colchunk 60: tiles 971..975 are zero-pad; run 971 (zeros, okc-masked)
    // so tmax stays even; 972+ skipped.
    const int tmax = (colchunk == 60) ? 12 : 16;

    auto loadg = [&](int bt, bf16x8& a, bf16x8& b) {
        const u16* g = tabt + (size_t)bt * TILE_SH;
        a = *(const bf16x8*)(g + tid * 8);
        b = *(const bf16x8*)(g + 2048 + tid * 8);
    };
    auto consume = [&](const short* lb, int bt) {
        f32x4 cc[4];
        #pragma unroll
        for (int s = 0; s < 4; ++s) cc[s] = f32x4{0.f, 0.f, 0.f, 0.f};
        #pragma unroll
        for (int kk = 0; kk < 8; ++kk) {
            const bf16x8 b = *(const bf16x8*)(lb + kk * 512 + quad * 128 + l15 * 8);
            cc[0] = __builtin_amdgcn_mfma_f32_16x16x32_bf16(af[0][kk], b, cc[0], 0, 0, 0);
            cc[1] = __builtin_amdgcn_mfma_f32_16x16x32_bf16(af[1][kk], b, cc[1], 0, 0, 0);
            cc[2] = __builtin_amdgcn_mfma_f32_16x16x32_bf16(af[2][kk], b, cc[2], 0, 0, 0);
            cc[3] = __builtin_amdgcn_mfma_f32_16x16x32_bf16(af[3][kk], b, cc[3], 0, 0, 0);
        }
        if (colchunk != 60) {
            if (bt < 312) {                    // all background
                #pragma unroll
                for (int s = 0; s < 4; ++s)
                    #pragma unroll
                    for (int r = 0; r < 4; ++r)
                        pbg[s * 4 + r] += exp2f(cc[s][r] * SCALE_LOG2E);
            } else if (bt > 312) {             // all non-bg
                #pragma unroll
                for (int s = 0; s < 4; ++s)
                    #pragma unroll
                    for (int r = 0; r < 4; ++r)
                        pnb[s * 4 + r] += exp2f(cc[s][r] * SCALE_LOG2E);
            } else {                           // tile 312: cols 4992..5007
                const bool isbg = l15 < 8;
                #pragma unroll
                for (int s = 0; s < 4; ++s)
                    #pragma unroll
                    for (int r = 0; r < 4; ++r) {
                        const float e = exp2f(cc[s][r] * SCALE_LOG2E);
                        pbg[s * 4 + r] += isbg ? e : 0.f;
                        pnb[s * 4 + r] += isbg ? 0.f : e;
                    }
            }
        } else {                               // last chunk: mask pad cols
            const bool okc = (bt * 16 + l15) < NTOT;
            #pragma unroll
            for (int s = 0; s < 4; ++s)
                #pragma unroll
                for (int r = 0; r < 4; ++r) {
                    const float e = exp2f(cc[s][r] * SCALE_LOG2E);
                    pnb[s * 4 + r] += okc ? e : 0.f;
                }
        }
    };

    bf16x8 r0, r1;
    loadg(bt0, r0, r1);

    #pragma unroll 1
    for (int tp = 0; tp < tmax; tp += 2) {
        // even tile -> lbuf0
        *(bf16x8*)(lbuf0 + tid * 8) = r0;
        *(bf16x8*)(lbuf0 + 2048 + tid * 8) = r1;
        __syncthreads();
        if (tp + 1 < tmax) loadg(bt0 + tp + 1, r0, r1);
        consume(lbuf0, bt0 + tp);

        // odd tile -> lbuf1
        *(bf16x8*)(lbuf1 + tid * 8) = r0;
        *(bf16x8*)(lbuf1 + 2048 + tid * 8) = r1;
        __syncthreads();
        if (tp + 2 < tmax) loadg(bt0 + tp + 2, r0, r1);
        consume(lbuf1, bt0 + tp + 1);
    }

    #pragma unroll
    for (int off = 1; off < 16; off <<= 1) {
        #pragma unroll
        for (int i = 0; i < 16; ++i) {
            pbg[i] += __shfl_xor(pbg[i], off);
            pnb[i] += __shfl_xor(pnb[i], off);
        }
    }
    if (l15 == 0) {
        #pragma unroll
        for (int s = 0; s < 4; ++s) {
            #pragma unroll
            for (int r = 0; r < 4; ++r) {
                const int row = (rowchunk * 16 + wave * 4 + s) * 16 + quad * 4 + r;
                atomic_add_f(&sum_bg[row], pbg[s * 4 + r]);
                atomic_add_f(&sum_nb[row], pnb[s * 4 + r]);
            }
        }
    }
}

// -------- Stage 1 (f32 fallback, round-4 structure, proven) ----------------
__global__ __launch_bounds__(256, 2) void score_f32_kernel(
    const float* __restrict__ inputs, const float* __restrict__ lut,
    const float* __restrict__ cq, const float* __restrict__ cqb,
    float* __restrict__ sum_bg, float* __restrict__ sum_nb)
{
    __shared__ __align__(16) short lds[32 * LPITCH];
    const int wave = threadIdx.x >> 6;
    const int lane = threadIdx.x & 63;
    const int l15  = lane & 15;
    const int quad = lane >> 4;
    const int rowbase = blockIdx.y * 256;
    const int colbase = blockIdx.x * 256;

    bf16x8 afrag[4][8];
    #pragma unroll 1
    for (int c = 0; c < 8; ++c) {
        __syncthreads();
        #pragma unroll
        for (int i = 0; i < 8; ++i) {
            const int lr = i * 4 + wave;
            const f32x4 v = *(const f32x4*)(inputs + (size_t)(rowbase + c * 32 + lr) * FEAT + lane * 4);
            bf16x4 h = { f2bf(v[0]), f2bf(v[1]), f2bf(v[2]), f2bf(v[3]) };
            *(bf16x4*)(&lds[lr * LPITCH + lane * 4]) = h;
        }
        __syncthreads();
        if ((c >> 1) == wave) {
            const int half = c & 1;
            #pragma unroll
            for (int j2 = 0; j2 < 2; ++j2) {
                const int lr = j2 * 16 + l15;
                #pragma unroll
                for (int kk = 0; kk < 8; ++kk)
                    afrag[half * 2 + j2][kk] =
                        *(const bf16x8*)(&lds[lr * LPITCH + kk * 32 + quad * 8]);
            }
        }
    }

    float pbg[16], pnb[16];
    #pragma unroll
    for (int i = 0; i < 16; ++i) { pbg[i] = 0.f; pnb[i] = 0.f; }

    #pragma unroll 1
    for (int s = 0; s < 8; ++s) {
        __syncthreads();
        #pragma unroll
        for (int i = 0; i < 8; ++i) {
            const int lc = i * 4 + wave;
            const f32x4 v = *(const f32x4*)(table_row(colbase + s * 32 + lc, lut, cq, cqb) + lane * 4);
            bf16x4 h = { f2bf(v[0]), f2bf(v[1]), f2bf(v[2]), f2bf(v[3]) };
            *(bf16x4*)(&lds[lc * LPITCH + lane * 4]) = h;
        }
        __syncthreads();

        #pragma unroll
        for (int st = 0; st < 2; ++st) {
            const int lc = st * 16 + l15;
            f32x4 cc[4];
            #pragma unroll
            for (int q = 0; q < 4; ++q) cc[q] = f32x4{0.f, 0.f, 0.f, 0.f};
            #pragma unroll
            for (int kk = 0; kk < 8; ++kk) {
                const bf16x8 b = *(const bf16x8*)(&lds[lc * LPITCH + kk * 32 + quad * 8]);
                cc[0] = __builtin_amdgcn_mfma_f32_16x16x32_bf16(afrag[0][kk], b, cc[0], 0, 0, 0);
                cc[1] = __builtin_amdgcn_mfma_f32_16x16x32_bf16(afrag[1][kk], b, cc[1], 0, 0, 0);
                cc[2] = __builtin_amdgcn_mfma_f32_16x16x32_bf16(afrag[2][kk], b, cc[2], 0, 0, 0);
                cc[3] = __builtin_amdgcn_mfma_f32_16x16x32_bf16(afrag[3][kk], b, cc[3], 0, 0, 0);
            }
            const int n = colbase + s * 32 + st * 16 + l15;
            const bool okc  = n < NTOT;
            const bool isbg = n < NBG;
            #pragma unroll
            for (int q = 0; q < 4; ++q) {
                #pragma unroll
                for (int r = 0; r < 4; ++r) {
                    float e = exp2f(cc[q][r] * SCALE_LOG2E);
                    e = okc ? e : 0.f;
                    pbg[q * 4 + r] += isbg ? e : 0.f;
                    pnb[q * 4 + r] += isbg ? 0.f : e;
                }
            }
        }
    }

    #pragma unroll
    for (int off = 1; off < 16; off <<= 1) {
        #pragma unroll
        for (int i = 0; i < 16; ++i) {
            pbg[i] += __shfl_xor(pbg[i], off);
            pnb[i] += __shfl_xor(pnb[i], off);
        }
    }
    if (l15 == 0) {
        #pragma unroll
        for (int q = 0; q < 4; ++q) {
            #pragma unroll
            for (int r = 0; r < 4; ++r) {
                const int row = rowbase + wave * 64 + q * 16 + quad * 4 + r;
                atomic_add_f(&sum_bg[row], pbg[q * 4 + r]);
                atomic_add_f(&sum_nb[row], pnb[q * 4 + r]);
            }
        }
    }
}

// -------- Stage 2: finalize (128 blocks; wave = 8 rows) + scalar fold ------
__global__ __launch_bounds__(256) void finalize_kernel(
    const float* __restrict__ inputs, const int* __restrict__ roi_label,
    const float* __restrict__ lut,
    const float* __restrict__ sum_bg, const float* __restrict__ sum_nb,
    float* __restrict__ accums, unsigned int* __restrict__ ticket,
    float* __restrict__ out)
{
    __shared__ float s_det[4], s_oim[4], s_nv[4];
    const int wid  = threadIdx.x >> 6;
    const int lane = threadIdx.x & 63;

    float det_a = 0.f, oim_a = 0.f, nv_a = 0.f;

    #pragma unroll 1
    for (int it = 0; it < 8; ++it) {
        const int row = blockIdx.x * 32 + wid * 8 + it;
        const int r   = roi_label[row];

        float dot = 0.f;
        {
            const int rc = r < 0 ? 0 : r;
            const f32x4 xi = *(const f32x4*)(inputs + (size_t)row * FEAT + lane * 4);
            const f32x4 li = *(const f32x4*)(lut + (size_t)rc * FEAT + lane * 4);
            #pragma unroll
            for (int jj = 0; jj < 4; ++jj)
                dot += bf2f((u16)f2bf(xi[jj])) * bf2f((u16)f2bf(li[jj]));
        }
        #pragma unroll
        for (int off = 32; off > 0; off >>= 1) dot += __shfl_xor(dot, off);

        if (lane == 0) {
            const float sbg = sum_bg[row];
            const float snb = sum_nb[row];
            const float inv = 1.f / (sbg + snb);
            const float cls0 = sbg * inv;
            const float cls1 = snb * inv;
            out[2 * row]     = cls0;
            out[2 * row + 1] = cls1;

            const float cs = (r >= -1) ? cls1 : cls0;
            const float om = 1.f - cs;
            det_a += -(0.25f * om * om * logf(cs)) * (1.f / (float)BATCH);
            nv_a  += (r >= -1) ? 1.f : 0.f;

            if (r >= 0) {
                const float logp = 30.f * dot - logf(snb);
                const float p    = expf(logp);
                const float om2  = 1.f - p;
                oim_a += -(0.25f * om2 * om2 * logp) * cls1 * cls1;
            }
        }
    }

    if (lane == 0) { s_det[wid] = det_a; s_oim[wid] = oim_a; s_nv[wid] = nv_a; }
    __syncthreads();
    if (threadIdx.x == 0) {
        atomic_add_f(&accums[0], s_det[0] + s_det[1] + s_det[2] + s_det[3]);
        atomic_add_f(&accums[1], s_oim[0] + s_oim[1] + s_oim[2] + s_oim[3]);
        atomic_add_f(&accums[2], s_nv[0] + s_nv[1] + s_nv[2] + s_nv[3]);
        __threadfence();
        const unsigned t = __hip_atomic_fetch_add(ticket, 1u, __ATOMIC_ACQ_REL,
                                                  __HIP_MEMORY_SCOPE_AGENT);
        if (t == gridDim.x - 1) {
            const float det = atomic_ld_f(&accums[0]);
            const float oim = atomic_ld_f(&accums[1]);
            float nv        = atomic_ld_f(&accums[2]);
            if (nv < 1.f) nv = 1.f;
            out[2 * BATCH]     = det;
            out[2 * BATCH + 1] = oim / nv;
        }
    }
}

extern "C" void kernel_launch(void* const* d_in, const int* in_sizes, int n_in,
                              void* d_out, int out_size, void* d_ws, size_t ws_size,
                              hipStream_t stream)
{
    const float* inputs = (const float*)d_in[0];
    const int*   roi    = (const int*)d_in[1];
    const float* lut    = (const float*)d_in[2];
    const float* cq     = (const float*)d_in[3];
    const float* cqb    = (const float*)d_in[4];
    float* out = (float*)d_out;

    if (ws_size >= (size_t)WS_NEED) {
        u16* tabt = (u16*)d_ws;
        u16* at   = (u16*)((char*)d_ws + TABT_BYTES);
        float* S  = (float*)((char*)d_ws + SUMS_OFF);
        prepass_kernel<<<PRE_BLOCKS, 256, 0, stream>>>(inputs, lut, cq, cqb, tabt, at, S);
        score_bf16_kernel<<<976, 256, 0, stream>>>(tabt, at, S, S + BATCH);
        finalize_kernel<<<128, 256, 0, stream>>>(
            inputs, roi, lut, S, S + BATCH, S + 2 * BATCH,
            (unsigned int*)(S + 2 * BATCH + 3), out);
    } else {
        float* S = (float*)d_ws;
        hipMemsetAsync(S, 0, SUMS_FLOATS * sizeof(float), stream);
        dim3 g1(61, 16);
        score_f32_kernel<<<g1, 256, 0, stream>>>(inputs, lut, cq, cqb, S, S + BATCH);
        finalize_kernel<<<128, 256, 0, stream>>>(
            inputs, roi, lut, S, S + BATCH, S + 2 * BATCH,
            (unsigned int*)(S + 2 * BATCH + 3), out);
    }
}